// Round 4
// baseline (1353.913 us; speedup 1.0000x reference)
//
#include <hip/hip_runtime.h>

typedef _Float16 f16;
typedef _Float16 f16x8 __attribute__((ext_vector_type(8)));
typedef float f32x4 __attribute__((ext_vector_type(4)));

#define NB 8
#define NC 256
#define NHW 4096
#define NPADN 4160   // 4096 + 1 exemplar + 63 zero-pad rows (multiple of 64)
#define NTOPK 150

// ---------------- prep: exe*1.2 -> Kt exemplar row + zero pad; tvec = sim @ exe12 (f64) ----
__global__ __launch_bounds__(256) void k_prep1(const float* __restrict__ exe,
                                               const float* __restrict__ sim,
                                               double* __restrict__ tvec,
                                               f16* __restrict__ Kt) {
  int b = blockIdx.x, c = threadIdx.x;
  __shared__ double e[NC];
  double v = (double)exe[b*NC + c] * 1.2;
  e[c] = v;
  Kt[((size_t)b*NPADN + NHW)*NC + c] = (f16)(float)v;
  for (int r = NHW + 1; r < NPADN; ++r)
    Kt[((size_t)b*NPADN + r)*NC + c] = (f16)0.f;
  __syncthreads();
  double acc = 0.0;
  for (int d = 0; d < NC; ++d) acc += (double)sim[c*NC + d] * e[d];
  tvec[b*NC + c] = acc;
}

// ---------------- simT[d][c] = sim[c][d]; Wh = v_weight (both f16) ----------------
__global__ __launch_bounds__(256) void k_small(const float* __restrict__ sim,
                                               const float* __restrict__ vw,
                                               f16* __restrict__ simT,
                                               f16* __restrict__ Wh) {
  int cc = blockIdx.x, d = threadIdx.x;
  simT[d*NC + cc] = (f16)sim[cc*NC + d];
  Wh[cc*NC + d]   = (f16)vw[cc*NC + d];
}

// ---------------- Kt[b][n][c] = f16(X[b][c][n]) + fused swe partials (f64) ----------------
__global__ __launch_bounds__(256) void k_transpose(const float* __restrict__ img,
                                                   const double* __restrict__ tvec,
                                                   f16* __restrict__ Kt,
                                                   double* __restrict__ swe4) {
  __shared__ float tile[64][65];
  __shared__ double red[64][5];
  int n0 = blockIdx.x*64, c0 = blockIdx.y*64, b = blockIdx.z;
  int t = threadIdx.x;
#pragma unroll
  for (int i = 0; i < 16; ++i) {
    int cl = (t>>6) + 4*i, nl = t&63;
    tile[cl][nl] = img[((size_t)b*NC + c0+cl)*NHW + n0 + nl];
  }
  __syncthreads();
#pragma unroll
  for (int i = 0; i < 16; ++i) {
    int nl = (t>>6) + 4*i, cl = t&63;
    Kt[((size_t)b*NPADN + n0+nl)*NC + c0 + cl] = (f16)tile[cl][nl];
  }
  // swe partial for this c-block: sum_{cl} tile[cl][m] * tvec[b][c0+cl]  (f64, fixed order)
  {
    int m = t&63, q = t>>6;
    double p = 0.0;
#pragma unroll
    for (int i = 0; i < 16; ++i) {
      int cl = q*16 + i;
      p += (double)tile[cl][m] * tvec[b*NC + c0 + cl];
    }
    red[m][q] = p;
  }
  __syncthreads();
  if (t < 64) {
    double s = red[t][0] + red[t][1] + red[t][2] + red[t][3];  // fixed order: deterministic
    swe4[((size_t)(b*4 + blockIdx.y))*NHW + n0 + t] = s;
  }
}

// ---------------- Q[b][m][d] = sum_c Kt[b][m][c] * sim[c][d]  (f16 MFMA) ----------------
__global__ __launch_bounds__(256) void k_qgemm(const f16* __restrict__ Kt,
                                               const f16* __restrict__ simT,
                                               f16* __restrict__ Q) {
  int b = blockIdx.y, m0 = blockIdx.x*64;
  int tid = threadIdx.x, w = tid>>6, l = tid&63, lm = l&15, g = l>>4;
  __shared__ f16 KtL[64*256];
  {
    const char* src = (const char*)(Kt + ((size_t)b*NPADN + m0)*NC);
#pragma unroll
    for (int p = 0; p < 8; ++p) {
      int row = p*8 + (tid>>5), c16 = tid&31;
      *(f16x8*)((char*)KtL + row*512 + ((c16*16) ^ ((row&7)<<4))) =
          *(const f16x8*)(src + row*512 + c16*16);
    }
  }
  __syncthreads();
  f16x8 a[8];
#pragma unroll
  for (int k = 0; k < 8; ++k) {
    int row = w*16 + lm;
    a[k] = *(const f16x8*)((const char*)KtL + row*512 + ((k*64 + g*16) ^ ((row&7)<<4)));
  }
  f32x4 acc[16];
#pragma unroll
  for (int i = 0; i < 16; ++i) acc[i] = (f32x4){0.f,0.f,0.f,0.f};
#pragma unroll
  for (int dt = 0; dt < 16; ++dt) {
    const f16* bb = simT + (size_t)(dt*16 + lm)*NC + g*8;
#pragma unroll
    for (int k = 0; k < 8; ++k) {
      f16x8 bf = *(const f16x8*)(bb + k*32);
      acc[dt] = __builtin_amdgcn_mfma_f32_16x16x32_f16(a[k], bf, acc[dt], 0,0,0);
    }
  }
  __syncthreads();
  f16* outl = KtL;  // reuse as store-bounce
#pragma unroll
  for (int dt = 0; dt < 16; ++dt)
#pragma unroll
    for (int r = 0; r < 4; ++r)
      outl[(w*16 + g*4 + r)*256 + dt*16 + lm] = (f16)acc[dt][r];
  __syncthreads();
  f16* dst = Q + ((size_t)b*NHW + m0)*NC;
#pragma unroll
  for (int p = 0; p < 8; ++p) {
    int row = p*8 + (tid>>5), c16 = tid&31;
    *(f16x8*)((char*)dst + row*512 + c16*16) =
        *(const f16x8*)((const char*)outl + row*512 + c16*16);
  }
}

// ---------------- Vt[b][d][n] = sum_c Wh[d][c] * Kt[b][n][c]  (+fused query gather) ----------
__global__ __launch_bounds__(256) void k_vgemm(const f16* __restrict__ Kt,
                                               const f16* __restrict__ Wh,
                                               const int* __restrict__ qids,
                                               f16* __restrict__ Vt,
                                               float* __restrict__ outQ) {
  int b = blockIdx.y, n0 = blockIdx.x*64;
  int tid = threadIdx.x, w = tid>>6, l = tid&63, lm = l&15, g = l>>4;
  __shared__ f16 KtL[4*64*72];   // staging (first 32KB region reused) + bounce with stride 72
  __shared__ int qid_s[NTOPK];
  if (tid < NTOPK) qid_s[tid] = qids[b*NTOPK + tid];
  {
    const char* src = (const char*)(Kt + ((size_t)b*NPADN + n0)*NC);
#pragma unroll
    for (int p = 0; p < 8; ++p) {
      int row = p*8 + (tid>>5), c16 = tid&31;
      *(f16x8*)((char*)KtL + row*512 + ((c16*16) ^ ((row&7)<<4))) =
          *(const f16x8*)(src + row*512 + c16*16);
    }
  }
  __syncthreads();
  f32x4 acc[4][4];
#pragma unroll
  for (int i = 0; i < 4; ++i)
#pragma unroll
    for (int j = 0; j < 4; ++j) acc[i][j] = (f32x4){0.f,0.f,0.f,0.f};
#pragma unroll
  for (int k = 0; k < 8; ++k) {
    f16x8 bf[4];
#pragma unroll
    for (int nt = 0; nt < 4; ++nt) {
      int row = nt*16 + lm;
      bf[nt] = *(const f16x8*)((const char*)KtL + row*512 + ((k*64 + g*16) ^ ((row&7)<<4)));
    }
#pragma unroll
    for (int dt = 0; dt < 4; ++dt) {
      f16x8 af = *(const f16x8*)(Wh + (size_t)(w*64 + dt*16 + lm)*NC + k*32 + g*8);
#pragma unroll
      for (int nt = 0; nt < 4; ++nt)
        acc[dt][nt] = __builtin_amdgcn_mfma_f32_16x16x32_f16(af, bf[nt], acc[dt][nt], 0,0,0);
    }
  }
  __syncthreads();
  f16* outl = KtL + w*4608;  // per-wave 64x72 bounce (stride 72 kills column-read conflicts)
#pragma unroll
  for (int dt = 0; dt < 4; ++dt)
#pragma unroll
    for (int nt = 0; nt < 4; ++nt)
#pragma unroll
      for (int r = 0; r < 4; ++r)
        outl[(dt*16 + g*4 + r)*72 + nt*16 + lm] = (f16)acc[dt][nt][r];
  __syncthreads();
  {
    f16* dst = Vt + ((size_t)(b*NC + w*64 + l))*NPADN + n0;
    const f16* srcl = outl + l*72;
#pragma unroll
    for (int c16 = 0; c16 < 8; ++c16)
      *(f16x8*)((char*)dst + c16*16) = *(const f16x8*)((const char*)srcl + c16*16);
  }
  // fused gather: queries[b][j][:] for any selected row in this n-block
  for (int j = 0; j < NTOPK; ++j) {
    int nl = qid_s[j] - n0;
    if (nl >= 0 && nl < 64) {
      int w2 = tid>>6, dl = tid&63;
      outQ[((size_t)b*NTOPK + j)*NC + tid] = (float)KtL[w2*4608 + dl*72 + nl];
    }
  }
}

// ---------------- top-150: register-resident cached argmax, 1 barrier/round ----------------
__global__ __launch_bounds__(256) void k_topk(const double* __restrict__ swe4,
                                              double* __restrict__ swe,
                                              int* __restrict__ qids) {
  int b = blockIdx.x, tid = threadIdx.x, w = tid>>6, l = tid&63;
  __shared__ double rv[2][4];
  __shared__ int    ri[2][4];
  double v[16];
#pragma unroll
  for (int j = 0; j < 16; ++j) {
    int idx = j*256 + tid;
    double s = swe4[((size_t)(b*4 + 0))*NHW + idx] + swe4[((size_t)(b*4 + 1))*NHW + idx]
             + swe4[((size_t)(b*4 + 2))*NHW + idx] + swe4[((size_t)(b*4 + 3))*NHW + idx];
    v[j] = s;
    swe[(size_t)b*NHW + idx] = s;
  }
  // cached per-thread argmax (strict > keeps smallest j on ties; idx grows with j)
  double bv = v[0]; int bj = 0;
#pragma unroll
  for (int j = 1; j < 16; ++j) if (v[j] > bv) { bv = v[j]; bj = j; }
  int bi = bj*256 + tid;

  for (int k = 0; k < NTOPK; ++k) {
    int p = k & 1;
    double mv = bv; int mi = bi;
#pragma unroll
    for (int off = 1; off < 64; off <<= 1) {
      double ov = __shfl_xor(mv, off);
      int oi = __shfl_xor(mi, off);
      if (ov > mv || (ov == mv && oi < mi)) { mv = ov; mi = oi; }
    }
    if (l == 0) { rv[p][w] = mv; ri[p][w] = mi; }
    __syncthreads();   // parity buffers -> single barrier per round is safe
    double fv = rv[p][0]; int fi = ri[p][0];
#pragma unroll
    for (int x = 1; x < 4; ++x)
      if (rv[p][x] > fv || (rv[p][x] == fv && ri[p][x] < fi)) { fv = rv[p][x]; fi = ri[p][x]; }
    if (tid == 0) qids[b*NTOPK + k] = fi;
    if ((fi & 255) == tid) {          // owner re-derives its cached max
#pragma unroll
      for (int j = 0; j < 16; ++j) if (fi == j*256 + tid) v[j] = -1e300;
      bv = v[0]; bj = 0;
#pragma unroll
      for (int j = 1; j < 16; ++j) if (v[j] > bv) { bv = v[j]; bj = j; }
      bi = bj*256 + tid;
    }
  }
}

// ---------------- flash attention: barrier-free, K/V direct from L2 ----------------
__global__ __launch_bounds__(256) void k_flash(const f16* __restrict__ Q,
                                               const f16* __restrict__ Kt,
                                               const f16* __restrict__ Vt,
                                               const double* __restrict__ swe,
                                               float* __restrict__ outI) {
  int bid = blockIdx.x;
  int b = bid & 7;              // batch -> XCD: one batch's K+V (4MB) fits one XCD L2
  int m0 = (bid >> 3) * 64;
  int tid = threadIdx.x, w = tid>>6, l = tid&63, lm = l&15, g = l>>4;

  __shared__ f16 PL[64*72];     // [m][n] P bounce, stride 72, wave-private rows

  const f16* Kb = Kt + (size_t)b*NPADN*NC;   // [n][c]
  const f16* Vb = Vt + (size_t)b*NC*NPADN;   // [d][n]

  f16x8 q[8];
  {
    const f16* qp = Q + ((size_t)b*NHW + m0 + w*16 + lm)*NC + g*8;
#pragma unroll
    for (int k = 0; k < 8; ++k) q[k] = *(const f16x8*)(qp + k*32);
  }
  f32x4 acc[16];
#pragma unroll
  for (int i = 0; i < 16; ++i) acc[i] = (f32x4){0.f,0.f,0.f,0.f};
  float mrun[4], lrun[4];
#pragma unroll
  for (int r = 0; r < 4; ++r) { mrun[r] = -1e30f; lrun[r] = 0.f; }

  for (int n0 = 0; n0 < NHW; n0 += 64) {
    __builtin_amdgcn_s_barrier();   // raw align barrier (no drain): keep 4 waves' K/V streams in L1 together
    // S = Q · K-tile: B-frags straight from L2 (16B/lane, 64B per g-group)
    f32x4 s[4];
#pragma unroll
    for (int nt = 0; nt < 4; ++nt) s[nt] = (f32x4){0.f,0.f,0.f,0.f};
#pragma unroll
    for (int k = 0; k < 8; ++k) {
#pragma unroll
      for (int nt = 0; nt < 4; ++nt) {
        f16x8 bf = *(const f16x8*)(Kb + (size_t)(n0 + nt*16 + lm)*NC + k*32 + g*8);
        s[nt] = __builtin_amdgcn_mfma_f32_16x16x32_f16(q[k], bf, s[nt], 0,0,0);
      }
    }
    // online softmax; rescale only when some row's max grew (exact: scale==1 otherwise)
    float mx[4];
#pragma unroll
    for (int r = 0; r < 4; ++r) {
      float m2 = fmaxf(fmaxf(s[0][r], s[1][r]), fmaxf(s[2][r], s[3][r]));
#pragma unroll
      for (int off = 1; off < 16; off <<= 1) m2 = fmaxf(m2, __shfl_xor(m2, off));
      mx[r] = m2;
    }
    bool grow = (mx[0] > mrun[0]) | (mx[1] > mrun[1]) | (mx[2] > mrun[2]) | (mx[3] > mrun[3]);
    if (__ballot(grow)) {
#pragma unroll
      for (int r = 0; r < 4; ++r) {
        float mnew = fmaxf(mrun[r], mx[r]);
        float scale = __expf(mrun[r] - mnew);
        mrun[r] = mnew;
        lrun[r] *= scale;
#pragma unroll
        for (int dt = 0; dt < 16; ++dt) acc[dt][r] *= scale;
      }
    }
#pragma unroll
    for (int r = 0; r < 4; ++r) {
      float rs = 0.f;
#pragma unroll
      for (int nt = 0; nt < 4; ++nt) {
        float p = __expf(s[nt][r] - mrun[r]);
        s[nt][r] = p;
        rs += p;
      }
#pragma unroll
      for (int off = 1; off < 16; off <<= 1) rs += __shfl_xor(rs, off);
      lrun[r] += rs;
    }
    // P write (wave-private rows: lgkmcnt dependency only, no barrier)
#pragma unroll
    for (int nt = 0; nt < 4; ++nt)
#pragma unroll
      for (int r = 0; r < 4; ++r)
        PL[(w*16 + g*4 + r)*72 + nt*16 + lm] = (f16)s[nt][r];
    // PV: acc += P · V-tile, V-frags straight from L2
#pragma unroll
    for (int ks = 0; ks < 2; ++ks) {
      f16x8 pa = *(const f16x8*)((const char*)PL + (w*16 + lm)*144 + ks*64 + g*16);
#pragma unroll
      for (int dt = 0; dt < 16; ++dt) {
        f16x8 vf = *(const f16x8*)(Vb + (size_t)(dt*16 + lm)*NPADN + n0 + ks*32 + g*8);
        acc[dt] = __builtin_amdgcn_mfma_f32_16x16x32_f16(pa, vf, acc[dt], 0,0,0);
      }
    }
  }
  // exemplar column n = 4096: exact f64 score; V column read per-lane from L2
#pragma unroll
  for (int r = 0; r < 4; ++r) {
    float sv = (float)swe[(size_t)b*NHW + m0 + w*16 + g*4 + r];
    float mnew = fmaxf(mrun[r], sv);
    float scale = __expf(mrun[r] - mnew);
    float pe = __expf(sv - mnew);
    mrun[r] = mnew;
    lrun[r] = lrun[r]*scale + pe;
#pragma unroll
    for (int dt = 0; dt < 16; ++dt) {
      float vex = (float)Vb[(size_t)(dt*16 + lm)*NPADN + NHW];
      acc[dt][r] = acc[dt][r]*scale + pe * vex;
    }
  }
  float* dst = outI + ((size_t)b*NHW + m0 + w*16)*NC;
#pragma unroll
  for (int dt = 0; dt < 16; ++dt)
#pragma unroll
    for (int r = 0; r < 4; ++r)
      dst[(size_t)(g*4 + r)*NC + dt*16 + lm] = acc[dt][r] / lrun[r];
}

extern "C" void kernel_launch(void* const* d_in, const int* in_sizes, int n_in,
                              void* d_out, int out_size, void* d_ws, size_t ws_size,
                              hipStream_t stream) {
  const float* img = (const float*)d_in[0];
  const float* exe = (const float*)d_in[1];
  const float* sim = (const float*)d_in[2];
  const float* vw  = (const float*)d_in[3];
  float* out = (float*)d_out;
  char* ws = (char*)d_ws;

  // workspace layout (256B aligned), total ~52.5 MB
  f16*    Kt   = (f16*)(ws);                 // 17,039,360 B
  f16*    Q    = (f16*)(ws + 17039360);      // 16,777,216 B
  f16*    Vt   = (f16*)(ws + 33816576);      // 17,039,360 B
  f16*    simT = (f16*)(ws + 50855936);      // 131,072 B
  f16*    Wh   = (f16*)(ws + 50987008);      // 131,072 B
  double* tvec = (double*)(ws + 51118080);   // 16,384 B
  double* swe  = (double*)(ws + 51134464);   // 262,144 B
  int*    qids = (int*)(ws + 51396608);      // 4,800 B (padded to 51,401,472)
  double* swe4 = (double*)(ws + 51401472);   // 1,048,576 B

  float* outImg = out;                       // (8,4096,256)
  float* outQ   = out + (size_t)NB*NHW*NC;   // (8,150,256)

  k_prep1<<<dim3(NB), dim3(256), 0, stream>>>(exe, sim, tvec, Kt);
  k_small<<<dim3(256), dim3(256), 0, stream>>>(sim, vw, simT, Wh);
  k_transpose<<<dim3(64,4,NB), dim3(256), 0, stream>>>(img, tvec, Kt, swe4);
  k_topk<<<dim3(NB), dim3(256), 0, stream>>>(swe4, swe, qids);
  k_qgemm<<<dim3(64,NB), dim3(256), 0, stream>>>(Kt, simT, Q);
  k_vgemm<<<dim3(65,NB), dim3(256), 0, stream>>>(Kt, Wh, qids, Vt, outQ);
  k_flash<<<dim3(512), dim3(256), 0, stream>>>(Q, Kt, Vt, swe, outImg);
}

// Round 5
// 903.206 us; speedup vs baseline: 1.4990x; 1.4990x over previous
//
#include <hip/hip_runtime.h>

typedef _Float16 f16;
typedef _Float16 f16x8 __attribute__((ext_vector_type(8)));
typedef float f32x4 __attribute__((ext_vector_type(4)));

#define NB 8
#define NC 256
#define NHW 4096
#define NPADN 4160   // 4096 + 1 exemplar + 63 zero-pad rows (multiple of 64)
#define NTOPK 150

#define GL16(gaddr, laddr) __builtin_amdgcn_global_load_lds( \
    (const __attribute__((address_space(1))) unsigned int*)(gaddr), \
    (__attribute__((address_space(3))) unsigned int*)(laddr), 16, 0, 0)

// ---------------- prep: exe*1.2 -> Kt exemplar row + zero pad; tvec = sim @ exe12 (f64) ----
__global__ __launch_bounds__(256) void k_prep1(const float* __restrict__ exe,
                                               const float* __restrict__ sim,
                                               double* __restrict__ tvec,
                                               f16* __restrict__ Kt) {
  int b = blockIdx.x, c = threadIdx.x;
  __shared__ double e[NC];
  double v = (double)exe[b*NC + c] * 1.2;
  e[c] = v;
  Kt[((size_t)b*NPADN + NHW)*NC + c] = (f16)(float)v;
  for (int r = NHW + 1; r < NPADN; ++r)
    Kt[((size_t)b*NPADN + r)*NC + c] = (f16)0.f;
  __syncthreads();
  double acc = 0.0;
  for (int d = 0; d < NC; ++d) acc += (double)sim[c*NC + d] * e[d];
  tvec[b*NC + c] = acc;
}

// ---------------- simT[d][c] = sim[c][d]; Wh = v_weight (both f16) ----------------
__global__ __launch_bounds__(256) void k_small(const float* __restrict__ sim,
                                               const float* __restrict__ vw,
                                               f16* __restrict__ simT,
                                               f16* __restrict__ Wh) {
  int cc = blockIdx.x, d = threadIdx.x;
  simT[d*NC + cc] = (f16)sim[cc*NC + d];
  Wh[cc*NC + d]   = (f16)vw[cc*NC + d];
}

// ---------------- Kt[b][n][c] = f16(X[b][c][n]) + fused swe partials (f64) ----------------
__global__ __launch_bounds__(256) void k_transpose(const float* __restrict__ img,
                                                   const double* __restrict__ tvec,
                                                   f16* __restrict__ Kt,
                                                   double* __restrict__ swe4) {
  __shared__ float tile[64][65];
  __shared__ double red[64][5];
  int n0 = blockIdx.x*64, c0 = blockIdx.y*64, b = blockIdx.z;
  int t = threadIdx.x;
#pragma unroll
  for (int i = 0; i < 16; ++i) {
    int cl = (t>>6) + 4*i, nl = t&63;
    tile[cl][nl] = img[((size_t)b*NC + c0+cl)*NHW + n0 + nl];
  }
  __syncthreads();
#pragma unroll
  for (int i = 0; i < 16; ++i) {
    int nl = (t>>6) + 4*i, cl = t&63;
    Kt[((size_t)b*NPADN + n0+nl)*NC + c0 + cl] = (f16)tile[cl][nl];
  }
  // swe partial for this c-block: sum_{cl} tile[cl][m] * tvec[b][c0+cl]  (f64, fixed order)
  {
    int m = t&63, q = t>>6;
    double p = 0.0;
#pragma unroll
    for (int i = 0; i < 16; ++i) {
      int cl = q*16 + i;
      p += (double)tile[cl][m] * tvec[b*NC + c0 + cl];
    }
    red[m][q] = p;
  }
  __syncthreads();
  if (t < 64) {
    double s = red[t][0] + red[t][1] + red[t][2] + red[t][3];  // fixed order: deterministic
    swe4[((size_t)(b*4 + blockIdx.y))*NHW + n0 + t] = s;
  }
}

// ---------------- Q[b][m][d] = sum_c Kt[b][m][c] * sim[c][d]  (f16 MFMA) ----------------
__global__ __launch_bounds__(256) void k_qgemm(const f16* __restrict__ Kt,
                                               const f16* __restrict__ simT,
                                               f16* __restrict__ Q) {
  int b = blockIdx.y, m0 = blockIdx.x*64;
  int tid = threadIdx.x, w = tid>>6, l = tid&63, lm = l&15, g = l>>4;
  __shared__ f16 KtL[64*256];
  {
    const char* src = (const char*)(Kt + ((size_t)b*NPADN + m0)*NC);
#pragma unroll
    for (int p = 0; p < 8; ++p) {
      int row = p*8 + (tid>>5), c16 = tid&31;
      *(f16x8*)((char*)KtL + row*512 + ((c16*16) ^ ((row&7)<<4))) =
          *(const f16x8*)(src + row*512 + c16*16);
    }
  }
  __syncthreads();
  f16x8 a[8];
#pragma unroll
  for (int k = 0; k < 8; ++k) {
    int row = w*16 + lm;
    a[k] = *(const f16x8*)((const char*)KtL + row*512 + ((k*64 + g*16) ^ ((row&7)<<4)));
  }
  f32x4 acc[16];
#pragma unroll
  for (int i = 0; i < 16; ++i) acc[i] = (f32x4){0.f,0.f,0.f,0.f};
#pragma unroll
  for (int dt = 0; dt < 16; ++dt) {
    const f16* bb = simT + (size_t)(dt*16 + lm)*NC + g*8;
#pragma unroll
    for (int k = 0; k < 8; ++k) {
      f16x8 bf = *(const f16x8*)(bb + k*32);
      acc[dt] = __builtin_amdgcn_mfma_f32_16x16x32_f16(a[k], bf, acc[dt], 0,0,0);
    }
  }
  __syncthreads();
  f16* outl = KtL;  // reuse as store-bounce
#pragma unroll
  for (int dt = 0; dt < 16; ++dt)
#pragma unroll
    for (int r = 0; r < 4; ++r)
      outl[(w*16 + g*4 + r)*256 + dt*16 + lm] = (f16)acc[dt][r];
  __syncthreads();
  f16* dst = Q + ((size_t)b*NHW + m0)*NC;
#pragma unroll
  for (int p = 0; p < 8; ++p) {
    int row = p*8 + (tid>>5), c16 = tid&31;
    *(f16x8*)((char*)dst + row*512 + c16*16) =
        *(const f16x8*)((const char*)outl + row*512 + c16*16);
  }
}

// ---------------- Vt[b][d][n] = sum_c Wh[d][c] * Kt[b][n][c]  (+fused query gather) ----------
__global__ __launch_bounds__(256) void k_vgemm(const f16* __restrict__ Kt,
                                               const f16* __restrict__ Wh,
                                               const int* __restrict__ qids,
                                               f16* __restrict__ Vt,
                                               float* __restrict__ outQ) {
  int b = blockIdx.y, n0 = blockIdx.x*64;
  int tid = threadIdx.x, w = tid>>6, l = tid&63, lm = l&15, g = l>>4;
  __shared__ f16 KtL[4*64*72];   // staging (first 32KB region reused) + bounce with stride 72
  __shared__ int qid_s[NTOPK];
  if (tid < NTOPK) qid_s[tid] = qids[b*NTOPK + tid];
  {
    const char* src = (const char*)(Kt + ((size_t)b*NPADN + n0)*NC);
#pragma unroll
    for (int p = 0; p < 8; ++p) {
      int row = p*8 + (tid>>5), c16 = tid&31;
      *(f16x8*)((char*)KtL + row*512 + ((c16*16) ^ ((row&7)<<4))) =
          *(const f16x8*)(src + row*512 + c16*16);
    }
  }
  __syncthreads();
  f32x4 acc[4][4];
#pragma unroll
  for (int i = 0; i < 4; ++i)
#pragma unroll
    for (int j = 0; j < 4; ++j) acc[i][j] = (f32x4){0.f,0.f,0.f,0.f};
#pragma unroll
  for (int k = 0; k < 8; ++k) {
    f16x8 bf[4];
#pragma unroll
    for (int nt = 0; nt < 4; ++nt) {
      int row = nt*16 + lm;
      bf[nt] = *(const f16x8*)((const char*)KtL + row*512 + ((k*64 + g*16) ^ ((row&7)<<4)));
    }
#pragma unroll
    for (int dt = 0; dt < 4; ++dt) {
      f16x8 af = *(const f16x8*)(Wh + (size_t)(w*64 + dt*16 + lm)*NC + k*32 + g*8);
#pragma unroll
      for (int nt = 0; nt < 4; ++nt)
        acc[dt][nt] = __builtin_amdgcn_mfma_f32_16x16x32_f16(af, bf[nt], acc[dt][nt], 0,0,0);
    }
  }
  __syncthreads();
  f16* outl = KtL + w*4608;  // per-wave 64x72 bounce (stride 72 kills column-read conflicts)
#pragma unroll
  for (int dt = 0; dt < 4; ++dt)
#pragma unroll
    for (int nt = 0; nt < 4; ++nt)
#pragma unroll
      for (int r = 0; r < 4; ++r)
        outl[(dt*16 + g*4 + r)*72 + nt*16 + lm] = (f16)acc[dt][nt][r];
  __syncthreads();
  {
    f16* dst = Vt + ((size_t)(b*NC + w*64 + l))*NPADN + n0;
    const f16* srcl = outl + l*72;
#pragma unroll
    for (int c16 = 0; c16 < 8; ++c16)
      *(f16x8*)((char*)dst + c16*16) = *(const f16x8*)((const char*)srcl + c16*16);
  }
  // fused gather: queries[b][j][:] for any selected row in this n-block
  for (int j = 0; j < NTOPK; ++j) {
    int nl = qid_s[j] - n0;
    if (nl >= 0 && nl < 64) {
      int w2 = tid>>6, dl = tid&63;
      outQ[((size_t)b*NTOPK + j)*NC + tid] = (float)KtL[w2*4608 + dl*72 + nl];
    }
  }
}

// ---------------- top-150: register-resident cached argmax, 1 barrier/round ----------------
__global__ __launch_bounds__(256) void k_topk(const double* __restrict__ swe4,
                                              double* __restrict__ swe,
                                              int* __restrict__ qids) {
  int b = blockIdx.x, tid = threadIdx.x, w = tid>>6, l = tid&63;
  __shared__ double rv[2][4];
  __shared__ int    ri[2][4];
  double v[16];
#pragma unroll
  for (int j = 0; j < 16; ++j) {
    int idx = j*256 + tid;
    double s = swe4[((size_t)(b*4 + 0))*NHW + idx] + swe4[((size_t)(b*4 + 1))*NHW + idx]
             + swe4[((size_t)(b*4 + 2))*NHW + idx] + swe4[((size_t)(b*4 + 3))*NHW + idx];
    v[j] = s;
    swe[(size_t)b*NHW + idx] = s;
  }
  // cached per-thread argmax (strict > keeps smallest j on ties; idx grows with j)
  double bv = v[0]; int bj = 0;
#pragma unroll
  for (int j = 1; j < 16; ++j) if (v[j] > bv) { bv = v[j]; bj = j; }
  int bi = bj*256 + tid;

  for (int k = 0; k < NTOPK; ++k) {
    int p = k & 1;
    double mv = bv; int mi = bi;
#pragma unroll
    for (int off = 1; off < 64; off <<= 1) {
      double ov = __shfl_xor(mv, off);
      int oi = __shfl_xor(mi, off);
      if (ov > mv || (ov == mv && oi < mi)) { mv = ov; mi = oi; }
    }
    if (l == 0) { rv[p][w] = mv; ri[p][w] = mi; }
    __syncthreads();   // parity buffers -> single barrier per round is safe
    double fv = rv[p][0]; int fi = ri[p][0];
#pragma unroll
    for (int x = 1; x < 4; ++x)
      if (rv[p][x] > fv || (rv[p][x] == fv && ri[p][x] < fi)) { fv = rv[p][x]; fi = ri[p][x]; }
    if (tid == 0) qids[b*NTOPK + k] = fi;
    if ((fi & 255) == tid) {          // owner re-derives its cached max
#pragma unroll
      for (int j = 0; j < 16; ++j) if (fi == j*256 + tid) v[j] = -1e300;
      bv = v[0]; bj = 0;
#pragma unroll
      for (int j = 1; j < 16; ++j) if (v[j] > bv) { bv = v[j]; bj = j; }
      bi = bj*256 + tid;
    }
  }
}

// ---------------- flash attention: 2 waves x 32 rows, DMA staging, LDS tiles ----------------
__global__ __launch_bounds__(128) void k_flash(const f16* __restrict__ Q,
                                               const f16* __restrict__ Kt,
                                               const f16* __restrict__ Vt,
                                               const double* __restrict__ swe,
                                               float* __restrict__ outI) {
  int bid = blockIdx.x;
  int b = bid & 7;              // batch -> XCD: one batch's K+V (4MB) fits one XCD L2
  int m0 = (bid >> 3) * 64;
  int tid = threadIdx.x, w = tid>>6, l = tid&63, lm = l&15, g = l>>4;

  __shared__ f16 KL[64*256];    // [n][c], XOR-swizzled (via pre-swizzled DMA source), 32 KB
  __shared__ f16 VL[256*64];    // [d][n], XOR-swizzled, 32 KB
  __shared__ f16 PL[64*72];     // [m][n], stride 72, wave-private rows, 9 KB

  const char* Kb = (const char*)(Kt + (size_t)b*NPADN*NC);   // [n][c] row = 512 B
  const char* Vb = (const char*)(Vt + (size_t)b*NC*NPADN);   // [d][n] row = 8320 B

  // Q: 32 rows/wave (mt=0,1), kept in registers
  f16x8 q[2][8];
#pragma unroll
  for (int mt = 0; mt < 2; ++mt) {
    const f16* qp = Q + ((size_t)b*NHW + m0 + w*32 + mt*16 + lm)*NC + g*8;
#pragma unroll
    for (int k = 0; k < 8; ++k) q[mt][k] = *(const f16x8*)(qp + k*32);
  }
  f32x4 acc[2][16];
#pragma unroll
  for (int mt = 0; mt < 2; ++mt)
#pragma unroll
    for (int i = 0; i < 16; ++i) acc[mt][i] = (f32x4){0.f,0.f,0.f,0.f};
  float mrun[2][4], lrun[2][4];
#pragma unroll
  for (int mt = 0; mt < 2; ++mt)
#pragma unroll
    for (int r = 0; r < 4; ++r) { mrun[mt][r] = -1e30f; lrun[mt][r] = 0.f; }

  // DMA staging: linear LDS dest (wave-uniform base + lane*16), inverse-XOR on global source.
  // K: 32 chunks of 1 KB (2 rows each); V: 32 chunks of 1 KB (8 rows each). Each wave does 16+16.
#define STAGE_TILE(n0)                                                                   \
  {                                                                                      \
    _Pragma("unroll")                                                                    \
    for (int j = 0; j < 16; ++j) {                                                       \
      int ch = w*16 + j;                                                                 \
      int krow = 2*ch + (l>>5);                                                          \
      GL16(Kb + (size_t)((n0) + krow)*512 + (((l&31)*16) ^ ((krow&7)<<4)),               \
           (f16*)KL + ch*512);                                                           \
      int vrow = 8*ch + (l>>3);                                                          \
      GL16(Vb + (size_t)vrow*(NPADN*2) + (n0)*2 + (((l&7)*16) ^ ((vrow&7)<<4)),          \
           (f16*)VL + ch*512);                                                           \
    }                                                                                    \
  }

  STAGE_TILE(0);   // prologue

  for (int t = 0; t < 64; ++t) {
    asm volatile("s_waitcnt vmcnt(0)" ::: "memory");   // own DMAs done (each wave staged its chunks)
    __builtin_amdgcn_s_barrier();                      // all waves' DMAs done -> tile t readable
    __builtin_amdgcn_sched_barrier(0);

    // S = Q · K-tile   (2 m-tiles x 64 n-cols; each K-frag feeds 2 MFMAs)
    f32x4 s[2][4];
#pragma unroll
    for (int mt = 0; mt < 2; ++mt)
#pragma unroll
      for (int nt = 0; nt < 4; ++nt) s[mt][nt] = (f32x4){0.f,0.f,0.f,0.f};
#pragma unroll
    for (int k = 0; k < 8; ++k) {
#pragma unroll
      for (int nt = 0; nt < 4; ++nt) {
        int row = nt*16 + lm;
        f16x8 bf = *(const f16x8*)((const char*)KL + row*512 + ((k*64 + g*16) ^ ((row&7)<<4)));
        s[0][nt] = __builtin_amdgcn_mfma_f32_16x16x32_f16(q[0][k], bf, s[0][nt], 0,0,0);
        s[1][nt] = __builtin_amdgcn_mfma_f32_16x16x32_f16(q[1][k], bf, s[1][nt], 0,0,0);
      }
    }
    // online softmax; rescale only when some row's max grew (exact: scale==1 otherwise)
    float mx[2][4];
#pragma unroll
    for (int mt = 0; mt < 2; ++mt)
#pragma unroll
      for (int r = 0; r < 4; ++r) {
        float m2 = fmaxf(fmaxf(s[mt][0][r], s[mt][1][r]), fmaxf(s[mt][2][r], s[mt][3][r]));
#pragma unroll
        for (int off = 1; off < 16; off <<= 1) m2 = fmaxf(m2, __shfl_xor(m2, off));
        mx[mt][r] = m2;
      }
    bool grow = false;
#pragma unroll
    for (int mt = 0; mt < 2; ++mt)
#pragma unroll
      for (int r = 0; r < 4; ++r) grow |= (mx[mt][r] > mrun[mt][r]);
    if (__ballot(grow)) {
#pragma unroll
      for (int mt = 0; mt < 2; ++mt)
#pragma unroll
        for (int r = 0; r < 4; ++r) {
          float mnew = fmaxf(mrun[mt][r], mx[mt][r]);
          float scale = __expf(mrun[mt][r] - mnew);
          mrun[mt][r] = mnew;
          lrun[mt][r] *= scale;
#pragma unroll
          for (int dt = 0; dt < 16; ++dt) acc[mt][dt][r] *= scale;
        }
    }
#pragma unroll
    for (int mt = 0; mt < 2; ++mt)
#pragma unroll
      for (int r = 0; r < 4; ++r) {
        float rs = 0.f;
#pragma unroll
        for (int nt = 0; nt < 4; ++nt) {
          float p = __expf(s[mt][nt][r] - mrun[mt][r]);
          s[mt][nt][r] = p;
          rs += p;
        }
#pragma unroll
        for (int off = 1; off < 16; off <<= 1) rs += __shfl_xor(rs, off);
        lrun[mt][r] += rs;
      }
    // P write (wave-private rows: lgkmcnt dependency only, no barrier)
#pragma unroll
    for (int mt = 0; mt < 2; ++mt)
#pragma unroll
      for (int nt = 0; nt < 4; ++nt)
#pragma unroll
        for (int r = 0; r < 4; ++r)
          PL[(w*32 + mt*16 + g*4 + r)*72 + nt*16 + lm] = (f16)s[mt][nt][r];
    // PV: acc += P · V-tile (each V-frag feeds 2 MFMAs)
#pragma unroll
    for (int ks = 0; ks < 2; ++ks) {
      f16x8 pa0 = *(const f16x8*)((const char*)PL + (w*32      + lm)*144 + ks*64 + g*16);
      f16x8 pa1 = *(const f16x8*)((const char*)PL + (w*32 + 16 + lm)*144 + ks*64 + g*16);
#pragma unroll
      for (int dt = 0; dt < 16; ++dt) {
        int row = dt*16 + lm;
        f16x8 vf = *(const f16x8*)((const char*)VL + row*128 + ((ks*64 + g*16) ^ ((row&7)<<4)));
        acc[0][dt] = __builtin_amdgcn_mfma_f32_16x16x32_f16(pa0, vf, acc[0][dt], 0,0,0);
        acc[1][dt] = __builtin_amdgcn_mfma_f32_16x16x32_f16(pa1, vf, acc[1][dt], 0,0,0);
      }
    }
    __builtin_amdgcn_sched_barrier(0);
    __builtin_amdgcn_s_barrier();      // all waves done reading tile t (no waitcnt drain)
    if (t < 63) STAGE_TILE((t+1)*64);  // DMA next tile; flies until top-of-loop vmcnt(0)
  }

  // exemplar column n = 4096: exact f64 score; V column read per-lane from L2
  float vex[16];
#pragma unroll
  for (int dt = 0; dt < 16; ++dt)
    vex[dt] = (float)((const f16*)Vb)[(size_t)(dt*16 + lm)*NPADN + NHW];
#pragma unroll
  for (int mt = 0; mt < 2; ++mt)
#pragma unroll
    for (int r = 0; r < 4; ++r) {
      float sv = (float)swe[(size_t)b*NHW + m0 + w*32 + mt*16 + g*4 + r];
      float mnew = fmaxf(mrun[mt][r], sv);
      float scale = __expf(mrun[mt][r] - mnew);
      float pe = __expf(sv - mnew);
      lrun[mt][r] = lrun[mt][r]*scale + pe;
#pragma unroll
      for (int dt = 0; dt < 16; ++dt)
        acc[mt][dt][r] = acc[mt][dt][r]*scale + pe * vex[dt];
    }
#pragma unroll
  for (int mt = 0; mt < 2; ++mt) {
    float* dst = outI + ((size_t)b*NHW + m0 + w*32 + mt*16)*NC;
#pragma unroll
    for (int dt = 0; dt < 16; ++dt)
#pragma unroll
      for (int r = 0; r < 4; ++r)
        dst[(size_t)(g*4 + r)*NC + dt*16 + lm] = acc[mt][dt][r] / lrun[mt][r];
  }
}

extern "C" void kernel_launch(void* const* d_in, const int* in_sizes, int n_in,
                              void* d_out, int out_size, void* d_ws, size_t ws_size,
                              hipStream_t stream) {
  const float* img = (const float*)d_in[0];
  const float* exe = (const float*)d_in[1];
  const float* sim = (const float*)d_in[2];
  const float* vw  = (const float*)d_in[3];
  float* out = (float*)d_out;
  char* ws = (char*)d_ws;

  // workspace layout (256B aligned), total ~52.5 MB
  f16*    Kt   = (f16*)(ws);                 // 17,039,360 B
  f16*    Q    = (f16*)(ws + 17039360);      // 16,777,216 B
  f16*    Vt   = (f16*)(ws + 33816576);      // 17,039,360 B
  f16*    simT = (f16*)(ws + 50855936);      // 131,072 B
  f16*    Wh   = (f16*)(ws + 50987008);      // 131,072 B
  double* tvec = (double*)(ws + 51118080);   // 16,384 B
  double* swe  = (double*)(ws + 51134464);   // 262,144 B
  int*    qids = (int*)(ws + 51396608);      // 4,800 B (padded to 51,401,472)
  double* swe4 = (double*)(ws + 51401472);   // 1,048,576 B

  float* outImg = out;                       // (8,4096,256)
  float* outQ   = out + (size_t)NB*NHW*NC;   // (8,150,256)

  k_prep1<<<dim3(NB), dim3(256), 0, stream>>>(exe, sim, tvec, Kt);
  k_small<<<dim3(256), dim3(256), 0, stream>>>(sim, vw, simT, Wh);
  k_transpose<<<dim3(64,4,NB), dim3(256), 0, stream>>>(img, tvec, Kt, swe4);
  k_topk<<<dim3(NB), dim3(256), 0, stream>>>(swe4, swe, qids);
  k_qgemm<<<dim3(64,NB), dim3(256), 0, stream>>>(Kt, simT, Q);
  k_vgemm<<<dim3(65,NB), dim3(256), 0, stream>>>(Kt, Wh, qids, Vt, outQ);
  k_flash<<<dim3(512), dim3(128), 0, stream>>>(Q, Kt, Vt, swe, outImg);
}

// Round 6
// 688.026 us; speedup vs baseline: 1.9678x; 1.3128x over previous
//
#include <hip/hip_runtime.h>

typedef _Float16 f16;
typedef _Float16 f16x8 __attribute__((ext_vector_type(8)));
typedef float f32x4 __attribute__((ext_vector_type(4)));

#define NB 8
#define NC 256
#define NHW 4096
#define NPADN 4160   // 4096 + 1 exemplar + 63 zero-pad rows (multiple of 64)
#define NTOPK 150

#define GL16(gaddr, laddr) __builtin_amdgcn_global_load_lds( \
    (const __attribute__((address_space(1))) unsigned int*)(gaddr), \
    (__attribute__((address_space(3))) unsigned int*)(laddr), 16, 0, 0)

// ---------------- prep: exe*1.2 -> Kt exemplar row + zero pad; tvec = sim @ exe12 (f64) ----
__global__ __launch_bounds__(256) void k_prep1(const float* __restrict__ exe,
                                               const float* __restrict__ sim,
                                               double* __restrict__ tvec,
                                               f16* __restrict__ Kt) {
  int b = blockIdx.x, c = threadIdx.x;
  __shared__ double e[NC];
  double v = (double)exe[b*NC + c] * 1.2;
  e[c] = v;
  Kt[((size_t)b*NPADN + NHW)*NC + c] = (f16)(float)v;
  for (int r = NHW + 1; r < NPADN; ++r)
    Kt[((size_t)b*NPADN + r)*NC + c] = (f16)0.f;
  __syncthreads();
  double acc = 0.0;
  for (int d = 0; d < NC; ++d) acc += (double)sim[c*NC + d] * e[d];
  tvec[b*NC + c] = acc;
}

// ---------------- simT[d][c] = sim[c][d]; Wh = v_weight (both f16) ----------------
__global__ __launch_bounds__(256) void k_small(const float* __restrict__ sim,
                                               const float* __restrict__ vw,
                                               f16* __restrict__ simT,
                                               f16* __restrict__ Wh) {
  int cc = blockIdx.x, d = threadIdx.x;
  simT[d*NC + cc] = (f16)sim[cc*NC + d];
  Wh[cc*NC + d]   = (f16)vw[cc*NC + d];
}

// ---------------- Kt[b][n][c] = f16(X[b][c][n]) + fused swe partials (f64) ----------------
__global__ __launch_bounds__(256) void k_transpose(const float* __restrict__ img,
                                                   const double* __restrict__ tvec,
                                                   f16* __restrict__ Kt,
                                                   double* __restrict__ swe4) {
  __shared__ float tile[64][65];
  __shared__ double red[64][5];
  int n0 = blockIdx.x*64, c0 = blockIdx.y*64, b = blockIdx.z;
  int t = threadIdx.x;
#pragma unroll
  for (int i = 0; i < 16; ++i) {
    int cl = (t>>6) + 4*i, nl = t&63;
    tile[cl][nl] = img[((size_t)b*NC + c0+cl)*NHW + n0 + nl];
  }
  __syncthreads();
#pragma unroll
  for (int i = 0; i < 16; ++i) {
    int nl = (t>>6) + 4*i, cl = t&63;
    Kt[((size_t)b*NPADN + n0+nl)*NC + c0 + cl] = (f16)tile[cl][nl];
  }
  // swe partial for this c-block: sum_{cl} tile[cl][m] * tvec[b][c0+cl]  (f64, fixed order)
  {
    int m = t&63, q = t>>6;
    double p = 0.0;
#pragma unroll
    for (int i = 0; i < 16; ++i) {
      int cl = q*16 + i;
      p += (double)tile[cl][m] * tvec[b*NC + c0 + cl];
    }
    red[m][q] = p;
  }
  __syncthreads();
  if (t < 64) {
    double s = red[t][0] + red[t][1] + red[t][2] + red[t][3];  // fixed order: deterministic
    swe4[((size_t)(b*4 + blockIdx.y))*NHW + n0 + t] = s;
  }
}

// ---------------- Q[b][m][d] = sum_c Kt[b][m][c] * sim[c][d]  (f16 MFMA) ----------------
__global__ __launch_bounds__(256) void k_qgemm(const f16* __restrict__ Kt,
                                               const f16* __restrict__ simT,
                                               f16* __restrict__ Q) {
  int b = blockIdx.y, m0 = blockIdx.x*64;
  int tid = threadIdx.x, w = tid>>6, l = tid&63, lm = l&15, g = l>>4;
  __shared__ f16 KtL[64*256];
  {
    const char* src = (const char*)(Kt + ((size_t)b*NPADN + m0)*NC);
#pragma unroll
    for (int p = 0; p < 8; ++p) {
      int row = p*8 + (tid>>5), c16 = tid&31;
      *(f16x8*)((char*)KtL + row*512 + ((c16*16) ^ ((row&7)<<4))) =
          *(const f16x8*)(src + row*512 + c16*16);
    }
  }
  __syncthreads();
  f16x8 a[8];
#pragma unroll
  for (int k = 0; k < 8; ++k) {
    int row = w*16 + lm;
    a[k] = *(const f16x8*)((const char*)KtL + row*512 + ((k*64 + g*16) ^ ((row&7)<<4)));
  }
  f32x4 acc[16];
#pragma unroll
  for (int i = 0; i < 16; ++i) acc[i] = (f32x4){0.f,0.f,0.f,0.f};
#pragma unroll
  for (int dt = 0; dt < 16; ++dt) {
    const f16* bb = simT + (size_t)(dt*16 + lm)*NC + g*8;
#pragma unroll
    for (int k = 0; k < 8; ++k) {
      f16x8 bf = *(const f16x8*)(bb + k*32);
      acc[dt] = __builtin_amdgcn_mfma_f32_16x16x32_f16(a[k], bf, acc[dt], 0,0,0);
    }
  }
  __syncthreads();
  f16* outl = KtL;  // reuse as store-bounce
#pragma unroll
  for (int dt = 0; dt < 16; ++dt)
#pragma unroll
    for (int r = 0; r < 4; ++r)
      outl[(w*16 + g*4 + r)*256 + dt*16 + lm] = (f16)acc[dt][r];
  __syncthreads();
  f16* dst = Q + ((size_t)b*NHW + m0)*NC;
#pragma unroll
  for (int p = 0; p < 8; ++p) {
    int row = p*8 + (tid>>5), c16 = tid&31;
    *(f16x8*)((char*)dst + row*512 + c16*16) =
        *(const f16x8*)((const char*)outl + row*512 + c16*16);
  }
}

// ---------------- Vt[b][d][n] = sum_c Wh[d][c] * Kt[b][n][c]  (+fused query gather) ----------
__global__ __launch_bounds__(256) void k_vgemm(const f16* __restrict__ Kt,
                                               const f16* __restrict__ Wh,
                                               const int* __restrict__ qids,
                                               f16* __restrict__ Vt,
                                               float* __restrict__ outQ) {
  int b = blockIdx.y, n0 = blockIdx.x*64;
  int tid = threadIdx.x, w = tid>>6, l = tid&63, lm = l&15, g = l>>4;
  __shared__ f16 KtL[4*64*72];   // staging (first 32KB region reused) + bounce with stride 72
  __shared__ int qid_s[NTOPK];
  if (tid < NTOPK) qid_s[tid] = qids[b*NTOPK + tid];
  {
    const char* src = (const char*)(Kt + ((size_t)b*NPADN + n0)*NC);
#pragma unroll
    for (int p = 0; p < 8; ++p) {
      int row = p*8 + (tid>>5), c16 = tid&31;
      *(f16x8*)((char*)KtL + row*512 + ((c16*16) ^ ((row&7)<<4))) =
          *(const f16x8*)(src + row*512 + c16*16);
    }
  }
  __syncthreads();
  f32x4 acc[4][4];
#pragma unroll
  for (int i = 0; i < 4; ++i)
#pragma unroll
    for (int j = 0; j < 4; ++j) acc[i][j] = (f32x4){0.f,0.f,0.f,0.f};
#pragma unroll
  for (int k = 0; k < 8; ++k) {
    f16x8 bf[4];
#pragma unroll
    for (int nt = 0; nt < 4; ++nt) {
      int row = nt*16 + lm;
      bf[nt] = *(const f16x8*)((const char*)KtL + row*512 + ((k*64 + g*16) ^ ((row&7)<<4)));
    }
#pragma unroll
    for (int dt = 0; dt < 4; ++dt) {
      f16x8 af = *(const f16x8*)(Wh + (size_t)(w*64 + dt*16 + lm)*NC + k*32 + g*8);
#pragma unroll
      for (int nt = 0; nt < 4; ++nt)
        acc[dt][nt] = __builtin_amdgcn_mfma_f32_16x16x32_f16(af, bf[nt], acc[dt][nt], 0,0,0);
    }
  }
  __syncthreads();
  f16* outl = KtL + w*4608;  // per-wave 64x72 bounce (stride 72 kills column-read conflicts)
#pragma unroll
  for (int dt = 0; dt < 4; ++dt)
#pragma unroll
    for (int nt = 0; nt < 4; ++nt)
#pragma unroll
      for (int r = 0; r < 4; ++r)
        outl[(dt*16 + g*4 + r)*72 + nt*16 + lm] = (f16)acc[dt][nt][r];
  __syncthreads();
  {
    f16* dst = Vt + ((size_t)(b*NC + w*64 + l))*NPADN + n0;
    const f16* srcl = outl + l*72;
#pragma unroll
    for (int c16 = 0; c16 < 8; ++c16)
      *(f16x8*)((char*)dst + c16*16) = *(const f16x8*)((const char*)srcl + c16*16);
  }
  // fused gather: queries[b][j][:] for any selected row in this n-block
  for (int j = 0; j < NTOPK; ++j) {
    int nl = qid_s[j] - n0;
    if (nl >= 0 && nl < 64) {
      int w2 = tid>>6, dl = tid&63;
      outQ[((size_t)b*NTOPK + j)*NC + tid] = (float)KtL[w2*4608 + dl*72 + nl];
    }
  }
}

// ---------------- top-150: register-resident cached argmax, 1 barrier/round ----------------
__global__ __launch_bounds__(256) void k_topk(const double* __restrict__ swe4,
                                              double* __restrict__ swe,
                                              int* __restrict__ qids) {
  int b = blockIdx.x, tid = threadIdx.x, w = tid>>6, l = tid&63;
  __shared__ double rv[2][4];
  __shared__ int    ri[2][4];
  double v[16];
#pragma unroll
  for (int j = 0; j < 16; ++j) {
    int idx = j*256 + tid;
    double s = swe4[((size_t)(b*4 + 0))*NHW + idx] + swe4[((size_t)(b*4 + 1))*NHW + idx]
             + swe4[((size_t)(b*4 + 2))*NHW + idx] + swe4[((size_t)(b*4 + 3))*NHW + idx];
    v[j] = s;
    swe[(size_t)b*NHW + idx] = s;
  }
  // cached per-thread argmax (strict > keeps smallest j on ties; idx grows with j)
  double bv = v[0]; int bj = 0;
#pragma unroll
  for (int j = 1; j < 16; ++j) if (v[j] > bv) { bv = v[j]; bj = j; }
  int bi = bj*256 + tid;

  for (int k = 0; k < NTOPK; ++k) {
    int p = k & 1;
    double mv = bv; int mi = bi;
#pragma unroll
    for (int off = 1; off < 64; off <<= 1) {
      double ov = __shfl_xor(mv, off);
      int oi = __shfl_xor(mi, off);
      if (ov > mv || (ov == mv && oi < mi)) { mv = ov; mi = oi; }
    }
    if (l == 0) { rv[p][w] = mv; ri[p][w] = mi; }
    __syncthreads();   // parity buffers -> single barrier per round is safe
    double fv = rv[p][0]; int fi = ri[p][0];
#pragma unroll
    for (int x = 1; x < 4; ++x)
      if (rv[p][x] > fv || (rv[p][x] == fv && ri[p][x] < fi)) { fv = rv[p][x]; fi = ri[p][x]; }
    if (tid == 0) qids[b*NTOPK + k] = fi;
    if ((fi & 255) == tid) {          // owner re-derives its cached max
#pragma unroll
      for (int j = 0; j < 16; ++j) if (fi == j*256 + tid) v[j] = -1e300;
      bv = v[0]; bj = 0;
#pragma unroll
      for (int j = 1; j < 16; ++j) if (v[j] > bv) { bv = v[j]; bj = j; }
      bi = bj*256 + tid;
    }
  }
}

// ---------------- flash attention: BM=128, 4 waves x 32 rows, double-buffered DMA ----------
__global__ __launch_bounds__(256, 1) void k_flash(const f16* __restrict__ Q,
                                                  const f16* __restrict__ Kt,
                                                  const f16* __restrict__ Vt,
                                                  const double* __restrict__ swe,
                                                  float* __restrict__ outI) {
  int bid = blockIdx.x;
  int b = bid & 7;              // batch -> XCD: one batch's K+V (4MB) fits one XCD L2
  int m0 = (bid >> 3) * 128;
  int tid = threadIdx.x, w = tid>>6, l = tid&63, lm = l&15, g = l>>4;

  __shared__ f16 KL[2][64*256]; // [buf][n][c], XOR-swizzled via pre-swizzled DMA source, 2x32 KB
  __shared__ f16 VL[2][64*256]; // [buf][d][n], XOR-swizzled, 2x32 KB
  __shared__ f16 PL[128*72];    // [m][n], stride 72, wave-private rows, 18 KB

  const char* Kb = (const char*)(Kt + (size_t)b*NPADN*NC);   // [n][c] row = 512 B
  const char* Vb = (const char*)(Vt + (size_t)b*NC*NPADN);   // [d][n] row = 8320 B

  // Q: 32 rows/wave (mt=0,1), kept in registers
  f16x8 q[2][8];
#pragma unroll
  for (int mt = 0; mt < 2; ++mt) {
    const f16* qp = Q + ((size_t)b*NHW + m0 + w*32 + mt*16 + lm)*NC + g*8;
#pragma unroll
    for (int k = 0; k < 8; ++k) q[mt][k] = *(const f16x8*)(qp + k*32);
  }
  f32x4 acc[2][16];
#pragma unroll
  for (int mt = 0; mt < 2; ++mt)
#pragma unroll
    for (int i = 0; i < 16; ++i) acc[mt][i] = (f32x4){0.f,0.f,0.f,0.f};
  float mrun[2][4], lrun[2][4];
#pragma unroll
  for (int mt = 0; mt < 2; ++mt)
#pragma unroll
    for (int r = 0; r < 4; ++r) { mrun[mt][r] = -1e30f; lrun[mt][r] = 0.f; }

  // DMA staging: 64 chunks of 1 KB (K: 32, V: 32); each wave stages 8+8.
  // Linear LDS dest (wave-uniform base + lane*16); inverse-XOR applied on global source.
#define STAGE_TILE(n0, KLb, VLb)                                                         \
  {                                                                                      \
    _Pragma("unroll")                                                                    \
    for (int j = 0; j < 8; ++j) {                                                        \
      int ch = w*8 + j;                                                                  \
      int krow = 2*ch + (l>>5);                                                          \
      GL16(Kb + (size_t)((n0) + krow)*512 + (((l&31)*16) ^ ((krow&7)<<4)),               \
           (f16*)(KLb) + ch*512);                                                        \
      int vrow = 8*ch + (l>>3);                                                          \
      GL16(Vb + (size_t)vrow*(NPADN*2) + (n0)*2 + (((l&7)*16) ^ ((vrow&7)<<4)),          \
           (f16*)(VLb) + ch*512);                                                        \
    }                                                                                    \
  }

  STAGE_TILE(0, KL[0], VL[0]);   // prologue

  for (int t = 0; t < 64; ++t) {
    const f16* KLc = KL[t&1];
    const f16* VLc = VL[t&1];
    asm volatile("s_waitcnt vmcnt(0)" ::: "memory");   // own tile-t DMAs landed
    __builtin_amdgcn_s_barrier();                      // all waves: tile t readable; buf^1 free
    __builtin_amdgcn_sched_barrier(0);
    if (t < 63) STAGE_TILE((t+1)*64, KL[(t+1)&1], VL[(t+1)&1]);  // flies under compute(t)
    __builtin_amdgcn_sched_barrier(0);

    // S = Q · K-tile   (2 m-tiles x 64 n-cols; each K-frag feeds 2 MFMAs)
    f32x4 s[2][4];
#pragma unroll
    for (int mt = 0; mt < 2; ++mt)
#pragma unroll
      for (int nt = 0; nt < 4; ++nt) s[mt][nt] = (f32x4){0.f,0.f,0.f,0.f};
#pragma unroll
    for (int k = 0; k < 8; ++k) {
#pragma unroll
      for (int nt = 0; nt < 4; ++nt) {
        int row = nt*16 + lm;
        f16x8 bf = *(const f16x8*)((const char*)KLc + row*512 + ((k*64 + g*16) ^ ((row&7)<<4)));
        s[0][nt] = __builtin_amdgcn_mfma_f32_16x16x32_f16(q[0][k], bf, s[0][nt], 0,0,0);
        s[1][nt] = __builtin_amdgcn_mfma_f32_16x16x32_f16(q[1][k], bf, s[1][nt], 0,0,0);
      }
    }
    // online softmax; rescale only when some row's max grew (exact: scale==1 otherwise)
    float mx[2][4];
#pragma unroll
    for (int mt = 0; mt < 2; ++mt)
#pragma unroll
      for (int r = 0; r < 4; ++r) {
        float m2 = fmaxf(fmaxf(s[mt][0][r], s[mt][1][r]), fmaxf(s[mt][2][r], s[mt][3][r]));
#pragma unroll
        for (int off = 1; off < 16; off <<= 1) m2 = fmaxf(m2, __shfl_xor(m2, off));
        mx[mt][r] = m2;
      }
    bool grow = false;
#pragma unroll
    for (int mt = 0; mt < 2; ++mt)
#pragma unroll
      for (int r = 0; r < 4; ++r) grow |= (mx[mt][r] > mrun[mt][r]);
    if (__ballot(grow)) {
#pragma unroll
      for (int mt = 0; mt < 2; ++mt)
#pragma unroll
        for (int r = 0; r < 4; ++r) {
          float mnew = fmaxf(mrun[mt][r], mx[mt][r]);
          float scale = __expf(mrun[mt][r] - mnew);
          mrun[mt][r] = mnew;
          lrun[mt][r] *= scale;
#pragma unroll
          for (int dt = 0; dt < 16; ++dt) acc[mt][dt][r] *= scale;
        }
    }
#pragma unroll
    for (int mt = 0; mt < 2; ++mt)
#pragma unroll
      for (int r = 0; r < 4; ++r) {
        float rs = 0.f;
#pragma unroll
        for (int nt = 0; nt < 4; ++nt) {
          float p = __expf(s[mt][nt][r] - mrun[mt][r]);
          s[mt][nt][r] = p;
          rs += p;
        }
#pragma unroll
        for (int off = 1; off < 16; off <<= 1) rs += __shfl_xor(rs, off);
        lrun[mt][r] += rs;
      }
    // P write (wave-private rows: lgkmcnt dependency only, no barrier)
#pragma unroll
    for (int mt = 0; mt < 2; ++mt)
#pragma unroll
      for (int nt = 0; nt < 4; ++nt)
#pragma unroll
        for (int r = 0; r < 4; ++r)
          PL[(w*32 + mt*16 + g*4 + r)*72 + nt*16 + lm] = (f16)s[mt][nt][r];
    // PV: acc += P · V-tile (each V-frag feeds 2 MFMAs)
#pragma unroll
    for (int ks = 0; ks < 2; ++ks) {
      f16x8 pa0 = *(const f16x8*)((const char*)PL + (w*32      + lm)*144 + ks*64 + g*16);
      f16x8 pa1 = *(const f16x8*)((const char*)PL + (w*32 + 16 + lm)*144 + ks*64 + g*16);
#pragma unroll
      for (int dt = 0; dt < 16; ++dt) {
        int row = dt*16 + lm;
        f16x8 vf = *(const f16x8*)((const char*)VLc + row*128 + ((ks*64 + g*16) ^ ((row&7)<<4)));
        acc[0][dt] = __builtin_amdgcn_mfma_f32_16x16x32_f16(pa0, vf, acc[0][dt], 0,0,0);
        acc[1][dt] = __builtin_amdgcn_mfma_f32_16x16x32_f16(pa1, vf, acc[1][dt], 0,0,0);
      }
    }
  }

  // exemplar column n = 4096: exact f64 score; V column read per-lane from L2
  float vex[16];
#pragma unroll
  for (int dt = 0; dt < 16; ++dt)
    vex[dt] = (float)((const f16*)Vb)[(size_t)(dt*16 + lm)*NPADN + NHW];
#pragma unroll
  for (int mt = 0; mt < 2; ++mt)
#pragma unroll
    for (int r = 0; r < 4; ++r) {
      float sv = (float)swe[(size_t)b*NHW + m0 + w*32 + mt*16 + g*4 + r];
      float mnew = fmaxf(mrun[mt][r], sv);
      float scale = __expf(mrun[mt][r] - mnew);
      float pe = __expf(sv - mnew);
      lrun[mt][r] = lrun[mt][r]*scale + pe;
#pragma unroll
      for (int dt = 0; dt < 16; ++dt)
        acc[mt][dt][r] = acc[mt][dt][r]*scale + pe * vex[dt];
    }
#pragma unroll
  for (int mt = 0; mt < 2; ++mt) {
    float* dst = outI + ((size_t)b*NHW + m0 + w*32 + mt*16)*NC;
#pragma unroll
    for (int dt = 0; dt < 16; ++dt)
#pragma unroll
      for (int r = 0; r < 4; ++r)
        dst[(size_t)(g*4 + r)*NC + dt*16 + lm] = acc[mt][dt][r] / lrun[mt][r];
  }
}

extern "C" void kernel_launch(void* const* d_in, const int* in_sizes, int n_in,
                              void* d_out, int out_size, void* d_ws, size_t ws_size,
                              hipStream_t stream) {
  const float* img = (const float*)d_in[0];
  const float* exe = (const float*)d_in[1];
  const float* sim = (const float*)d_in[2];
  const float* vw  = (const float*)d_in[3];
  float* out = (float*)d_out;
  char* ws = (char*)d_ws;

  // workspace layout (256B aligned), total ~52.5 MB
  f16*    Kt   = (f16*)(ws);                 // 17,039,360 B
  f16*    Q    = (f16*)(ws + 17039360);      // 16,777,216 B
  f16*    Vt   = (f16*)(ws + 33816576);      // 17,039,360 B
  f16*    simT = (f16*)(ws + 50855936);      // 131,072 B
  f16*    Wh   = (f16*)(ws + 50987008);      // 131,072 B
  double* tvec = (double*)(ws + 51118080);   // 16,384 B
  double* swe  = (double*)(ws + 51134464);   // 262,144 B
  int*    qids = (int*)(ws + 51396608);      // 4,800 B (padded to 51,401,472)
  double* swe4 = (double*)(ws + 51401472);   // 1,048,576 B

  float* outImg = out;                       // (8,4096,256)
  float* outQ   = out + (size_t)NB*NHW*NC;   // (8,150,256)

  k_prep1<<<dim3(NB), dim3(256), 0, stream>>>(exe, sim, tvec, Kt);
  k_small<<<dim3(256), dim3(256), 0, stream>>>(sim, vw, simT, Wh);
  k_transpose<<<dim3(64,4,NB), dim3(256), 0, stream>>>(img, tvec, Kt, swe4);
  k_topk<<<dim3(NB), dim3(256), 0, stream>>>(swe4, swe, qids);
  k_qgemm<<<dim3(64,NB), dim3(256), 0, stream>>>(Kt, simT, Q);
  k_vgemm<<<dim3(65,NB), dim3(256), 0, stream>>>(Kt, Wh, qids, Vt, outQ);
  k_flash<<<dim3(256), dim3(256), 0, stream>>>(Q, Kt, Vt, swe, outImg);
}